// Round 1
// baseline (1481.292 us; speedup 1.0000x reference)
//
#include <hip/hip_runtime.h>
#include <math.h>

// Problem constants
#define NB 16
#define NT 2048
#define NMEL 80
#define NPOS 512          // stacked positions per batch
#define INDIM 320
#define EDIM 16
#define NEMB 8192
#define ENCD 512
#define MROWS (NB*511)    // 8176 logit rows (b, t'=0..510)
#define MPAD 8192
#define NVT 32            // v tiles
#define BN 256            // v tile size
#define BM 64             // m tile size
#define BK 32             // k tile size

// ---------------- Kernel A: codes (stack -> LN -> proj -> normalize -> argmin dist) ----
__global__ __launch_bounds__(256) void codes_kernel(
    const float* __restrict__ feats, const float* __restrict__ proj,
    const float* __restrict__ emb, int* __restrict__ codes)
{
    __shared__ float embS[512][EDIM + 1];  // +1 pad: conflict-free strided reads
    const int tid  = threadIdx.x;
    const int lane = tid & 63;
    const int wave = tid >> 6;
    const int gbase = blockIdx.x * 16 + wave * 4;   // 4 positions per wave

    float yn[4][EDIM];
    float x2[4];

    #pragma unroll
    for (int pi = 0; pi < 4; ++pi) {
        const int g = gbase + pi;
        const int b = g >> 9;      // /512
        const int i = g & 511;
        float xv[5];
        float s = 0.f, sq = 0.f;
        #pragma unroll
        for (int q = 0; q < 5; ++q) {
            const int d = lane + 64 * q;            // 0..319
            const int j = d / 80, k = d - j * 80;
            const float v = feats[((b * NT) + (i * 4 + j)) * NMEL + k];
            xv[q] = v; s += v; sq += v * v;
        }
        for (int m = 1; m < 64; m <<= 1) { s += __shfl_xor(s, m); sq += __shfl_xor(sq, m); }
        const float mean = s * (1.0f / 320.0f);
        const float var  = sq * (1.0f / 320.0f) - mean * mean;
        const float rstd = rsqrtf(var + 1e-6f);

        float acc[EDIM];
        #pragma unroll
        for (int e = 0; e < EDIM; ++e) acc[e] = 0.f;
        #pragma unroll
        for (int q = 0; q < 5; ++q) {
            const int d = lane + 64 * q;
            const float xn = (xv[q] - mean) * rstd;
            #pragma unroll
            for (int e = 0; e < EDIM; ++e) acc[e] += xn * proj[d * EDIM + e];
        }
        for (int m = 1; m < 64; m <<= 1) {
            #pragma unroll
            for (int e = 0; e < EDIM; ++e) acc[e] += __shfl_xor(acc[e], m);
        }
        float nsq = 0.f;
        #pragma unroll
        for (int e = 0; e < EDIM; ++e) nsq += acc[e] * acc[e];
        const float inv = 1.0f / (sqrtf(nsq) + 1e-8f);
        float xs = 0.f;
        #pragma unroll
        for (int e = 0; e < EDIM; ++e) { const float t = acc[e] * inv; yn[pi][e] = t; xs += t * t; }
        x2[pi] = xs;
    }

    float mind[4]; int mini[4];
    #pragma unroll
    for (int pi = 0; pi < 4; ++pi) { mind[pi] = INFINITY; mini[pi] = 0x7fffffff; }

    for (int c = 0; c < 16; ++c) {           // 16 chunks of 512 embeddings
        __syncthreads();
        #pragma unroll
        for (int r = 0; r < 32; ++r) {
            const int flat = r * 256 + tid;          // 0..8191
            const int vl = flat >> 4, e = flat & 15;
            embS[vl][e] = emb[c * 8192 + flat];
        }
        __syncthreads();
        #pragma unroll
        for (int q = 0; q < 8; ++q) {
            const int vl = lane + 64 * q;
            float ev[EDIM];
            float e2 = 0.f;
            #pragma unroll
            for (int e = 0; e < EDIM; ++e) { const float t = embS[vl][e]; ev[e] = t; e2 += t * t; }
            const int v = c * 512 + vl;
            #pragma unroll
            for (int pi = 0; pi < 4; ++pi) {
                float dot = 0.f;
                #pragma unroll
                for (int e = 0; e < EDIM; ++e) dot += yn[pi][e] * ev[e];
                const float dist = x2[pi] - 2.0f * dot + e2;
                if (dist < mind[pi]) { mind[pi] = dist; mini[pi] = v; }
            }
        }
    }
    for (int m = 1; m < 64; m <<= 1) {
        #pragma unroll
        for (int pi = 0; pi < 4; ++pi) {
            const float ov = __shfl_xor(mind[pi], m);
            const int   oi = __shfl_xor(mini[pi], m);
            if (ov < mind[pi] || (ov == mind[pi] && oi < mini[pi])) { mind[pi] = ov; mini[pi] = oi; }
        }
    }
    if (lane == 0) {
        #pragma unroll
        for (int pi = 0; pi < 4; ++pi) codes[gbase + pi] = mini[pi];
    }
}

// ---------------- Kernel: zero presence ----------------
__global__ void zero_presence(int* __restrict__ presence)
{
    presence[blockIdx.x * 256 + threadIdx.x] = 0;
}

// ---------------- Kernel B: fused GEMM + per-tile softmax partials ----------------
__global__ __launch_bounds__(256) void logits_kernel(
    const float* __restrict__ enc, const float* __restrict__ tno,
    const int* __restrict__ codes,
    float* __restrict__ pm, float* __restrict__ ps, int* __restrict__ pidx,
    float* __restrict__ tgtlog)
{
    __shared__ float As[BK][BM];   // [32][64]
    __shared__ float Bs[BK][BN];   // [32][256]
    const int tid = threadIdx.x;
    const int vt = blockIdx.x;          // 0..31
    const int mt = blockIdx.y;          // 0..127
    const int v0 = vt * BN;
    const int m0 = mt * BM;
    const int ty = tid >> 5;            // 0..7  (row group)
    const int tx = tid & 31;            // 0..31 (col group)

    // A-load mapping: 2 rows x 4 k per thread
    const int arow = tid >> 3;          // 0..31
    const int ak   = (tid & 7) * 4;     // 0..28
    long abase[2]; bool aval[2];
    #pragma unroll
    for (int l = 0; l < 2; ++l) {
        const int m = m0 + arow + l * 32;
        aval[l] = (m < MROWS);
        const int b = aval[l] ? (m / 511) : 0;
        const int t = aval[l] ? (m % 511) : 0;
        abase[l] = (long)(b * ENCD + t) * ENCD;
    }
    // B-load mapping: 8 x (1 k row, 4 v) per thread
    const int bk0 = tid >> 6;           // 0..3
    const int bv  = (tid & 63) * 4;     // 0..252

    float acc[8][8];
    #pragma unroll
    for (int i = 0; i < 8; ++i)
        #pragma unroll
        for (int j = 0; j < 8; ++j) acc[i][j] = 0.f;

    for (int k0 = 0; k0 < ENCD; k0 += BK) {
        #pragma unroll
        for (int l = 0; l < 2; ++l) {
            float4 a = make_float4(0.f, 0.f, 0.f, 0.f);
            if (aval[l]) a = *(const float4*)&enc[abase[l] + k0 + ak];
            As[ak + 0][arow + l * 32] = a.x;
            As[ak + 1][arow + l * 32] = a.y;
            As[ak + 2][arow + l * 32] = a.z;
            As[ak + 3][arow + l * 32] = a.w;
        }
        #pragma unroll
        for (int l = 0; l < 8; ++l) {
            const int k = bk0 + l * 4;
            *(float4*)&Bs[k][bv] = *(const float4*)&tno[(long)(k0 + k) * NEMB + v0 + bv];
        }
        __syncthreads();
        #pragma unroll
        for (int kk = 0; kk < BK; ++kk) {
            float af[8], bf[8];
            #pragma unroll
            for (int i = 0; i < 8; ++i) af[i] = As[kk][ty + 8 * i];
            #pragma unroll
            for (int j = 0; j < 8; ++j) bf[j] = Bs[kk][tx + 32 * j];
            #pragma unroll
            for (int i = 0; i < 8; ++i)
                #pragma unroll
                for (int j = 0; j < 8; ++j) acc[i][j] += af[i] * bf[j];
        }
        __syncthreads();
    }

    // Epilogue: per-row (64 rows) partial max / first-argmax / sumexp over this 256-v tile
    #pragma unroll
    for (int i = 0; i < 8; ++i) {
        const int m = m0 + ty + 8 * i;
        float lm = -INFINITY; int li = 0x7fffffff;
        #pragma unroll
        for (int j = 0; j < 8; ++j) {
            const float v = acc[i][j];
            if (v > lm) { lm = v; li = v0 + tx + 32 * j; }   // ascending v per thread -> first max kept
        }
        #pragma unroll
        for (int mk = 16; mk >= 1; mk >>= 1) {
            const float ov = __shfl_xor(lm, mk);
            const int   oi = __shfl_xor(li, mk);
            if (ov > lm || (ov == lm && oi < li)) { lm = ov; li = oi; }
        }
        float le = 0.f;
        #pragma unroll
        for (int j = 0; j < 8; ++j) le += expf(acc[i][j] - lm);
        #pragma unroll
        for (int mk = 16; mk >= 1; mk >>= 1) le += __shfl_xor(le, mk);

        if (m < MROWS) {
            if (tx == 0) { pm[vt * MPAD + m] = lm; ps[vt * MPAD + m] = le; pidx[vt * MPAD + m] = li; }
            const int b = m / 511, t = m % 511;
            const int tv = codes[b * NPOS + t + 1];
            const int rel = tv - v0;
            if (rel >= 0 && rel < BN && (rel & 31) == tx) {
                tgtlog[m] = acc[i][rel >> 5];
            }
        }
    }
}

// ---------------- Phase 2: combine tile partials per row ----------------
__global__ __launch_bounds__(256) void combine_kernel(
    const float* __restrict__ pm, const float* __restrict__ ps,
    const int* __restrict__ pidx, const float* __restrict__ tgtlog,
    const int* __restrict__ codes, const int* __restrict__ lens,
    float* __restrict__ rnll, float* __restrict__ rcorr, float* __restrict__ rmf,
    int* __restrict__ presence)
{
    const int g = blockIdx.x * 256 + threadIdx.x;
    if (g >= MROWS) return;
    float gm = -INFINITY; int gi = 0;
    #pragma unroll 4
    for (int nt = 0; nt < NVT; ++nt) {
        const float v = pm[nt * MPAD + g];
        if (v > gm) { gm = v; gi = pidx[nt * MPAD + g]; }   // earlier tile wins on ties (lower v)
    }
    float S = 0.f;
    #pragma unroll 4
    for (int nt = 0; nt < NVT; ++nt) S += ps[nt * MPAD + g] * expf(pm[nt * MPAD + g] - gm);
    const float lse = gm + logf(S);
    const int b = g / 511, t = g % 511;
    const int tv = codes[b * NPOS + t + 1];
    const float nll = lse - tgtlog[g];
    const int L = lens[b];
    const int s = t + 1;
    const bool mf = (s < (L / 4)) && (4 * s + 3 < L);
    rnll[g]  = mf ? nll : 0.f;
    rcorr[g] = (mf && gi == tv) ? 1.f : 0.f;
    rmf[g]   = mf ? 1.f : 0.f;
    presence[mf ? tv : 0] = 1;
}

// ---------------- Phase 3: final reduction -> 4 scalars ----------------
__global__ __launch_bounds__(256) void finalize_kernel(
    const float* __restrict__ rnll, const float* __restrict__ rcorr,
    const float* __restrict__ rmf, const int* __restrict__ presence,
    float* __restrict__ out)
{
    __shared__ float sh0[256], sh1[256], sh2[256];
    __shared__ int shp[256];
    const int tid = threadIdx.x;
    float sn = 0.f, sc = 0.f, sm = 0.f; int pp = 0;
    for (int g = tid; g < MROWS; g += 256) { sn += rnll[g]; sc += rcorr[g]; sm += rmf[g]; }
    for (int v = tid; v < NEMB; v += 256) pp += presence[v];
    sh0[tid] = sn; sh1[tid] = sc; sh2[tid] = sm; shp[tid] = pp;
    __syncthreads();
    for (int s = 128; s > 0; s >>= 1) {
        if (tid < s) { sh0[tid] += sh0[tid + s]; sh1[tid] += sh1[tid + s]; sh2[tid] += sh2[tid + s]; shp[tid] += shp[tid + s]; }
        __syncthreads();
    }
    if (tid == 0) {
        const float Sm = sh2[0];
        out[0] = sh0[0] / Sm;        // loss
        out[1] = sh1[0] / Sm;        // codes_acc
        out[2] = Sm;                 // num_codes (NCB=1)
        out[3] = (float)shp[0];      // uniq_num_codes
    }
}

extern "C" void kernel_launch(void* const* d_in, const int* in_sizes, int n_in,
                              void* d_out, int out_size, void* d_ws, size_t ws_size,
                              hipStream_t stream) {
    const float* feats = (const float*)d_in[0];
    const int*   lens  = (const int*)d_in[1];
    const float* enc   = (const float*)d_in[2];
    const float* proj  = (const float*)d_in[3];
    const float* emb   = (const float*)d_in[4];
    const float* tno   = (const float*)d_in[5];
    float* out = (float*)d_out;

    int* codes     = (int*)d_ws;
    int* presence  = codes + NB * NPOS;
    int* pidx      = presence + NEMB;
    float* pm      = (float*)(pidx + NVT * MPAD);
    float* ps      = pm + NVT * MPAD;
    float* tgtlog  = ps + NVT * MPAD;
    float* rnll    = tgtlog + MPAD;
    float* rcorr   = rnll + MPAD;
    float* rmf     = rcorr + MPAD;

    hipLaunchKernelGGL(codes_kernel, dim3(512), dim3(256), 0, stream, feats, proj, emb, codes);
    hipLaunchKernelGGL(zero_presence, dim3(NEMB / 256), dim3(256), 0, stream, presence);
    hipLaunchKernelGGL(logits_kernel, dim3(NVT, 128), dim3(256), 0, stream, enc, tno, codes, pm, ps, pidx, tgtlog);
    hipLaunchKernelGGL(combine_kernel, dim3((MROWS + 255) / 256), dim3(256), 0, stream,
                       pm, ps, pidx, tgtlog, codes, lens, rnll, rcorr, rmf, presence);
    hipLaunchKernelGGL(finalize_kernel, dim3(1), dim3(256), 0, stream, rnll, rcorr, rmf, presence, out);
}

// Round 2
// 564.995 us; speedup vs baseline: 2.6218x; 2.6218x over previous
//
#include <hip/hip_runtime.h>
#include <math.h>

typedef __attribute__((ext_vector_type(4))) float f32x4;
typedef __attribute__((ext_vector_type(8))) short bf16x8;

// Problem constants
#define NB 16
#define NT 2048
#define NMEL 80
#define NPOS 512          // stacked positions per batch
#define EDIM 16
#define NEMB 8192
#define ENCD 512
#define MROWS (NB*511)    // 8176 logit rows
#define MPAD 8192
#define NVT 64            // 8192 / 128 col tiles

__device__ __forceinline__ unsigned short f2bf(float x) {
    union { float f; unsigned u; } v; v.f = x;
    unsigned r = v.u + 0x7fffu + ((v.u >> 16) & 1u);
    return (unsigned short)(r >> 16);
}

__device__ __forceinline__ void gl_lds16(const void* gsrc, void* lds) {
    __builtin_amdgcn_global_load_lds(
        (const __attribute__((address_space(1))) unsigned int*)gsrc,
        (__attribute__((address_space(3))) unsigned int*)lds,
        16, 0, 0);
}

// ---------------- Kernel A: codes (stack -> LN -> proj -> normalize -> argmin dist) ----
__global__ __launch_bounds__(256) void codes_kernel(
    const float* __restrict__ feats, const float* __restrict__ proj,
    const float* __restrict__ emb, int* __restrict__ codes)
{
    __shared__ float embS[512][EDIM + 1];
    const int tid  = threadIdx.x;
    const int lane = tid & 63;
    const int wave = tid >> 6;
    const int gbase = blockIdx.x * 16 + wave * 4;

    float yn[4][EDIM];
    float x2[4];

    #pragma unroll
    for (int pi = 0; pi < 4; ++pi) {
        const int g = gbase + pi;
        const int b = g >> 9;
        const int i = g & 511;
        float xv[5];
        float s = 0.f, sq = 0.f;
        #pragma unroll
        for (int q = 0; q < 5; ++q) {
            const int d = lane + 64 * q;
            const int j = d / 80, k = d - j * 80;
            const float v = feats[((b * NT) + (i * 4 + j)) * NMEL + k];
            xv[q] = v; s += v; sq += v * v;
        }
        for (int m = 1; m < 64; m <<= 1) { s += __shfl_xor(s, m); sq += __shfl_xor(sq, m); }
        const float mean = s * (1.0f / 320.0f);
        const float var  = sq * (1.0f / 320.0f) - mean * mean;
        const float rstd = rsqrtf(var + 1e-6f);

        float acc[EDIM];
        #pragma unroll
        for (int e = 0; e < EDIM; ++e) acc[e] = 0.f;
        #pragma unroll
        for (int q = 0; q < 5; ++q) {
            const int d = lane + 64 * q;
            const float xn = (xv[q] - mean) * rstd;
            #pragma unroll
            for (int e = 0; e < EDIM; ++e) acc[e] += xn * proj[d * EDIM + e];
        }
        for (int m = 1; m < 64; m <<= 1) {
            #pragma unroll
            for (int e = 0; e < EDIM; ++e) acc[e] += __shfl_xor(acc[e], m);
        }
        float nsq = 0.f;
        #pragma unroll
        for (int e = 0; e < EDIM; ++e) nsq += acc[e] * acc[e];
        const float inv = 1.0f / (sqrtf(nsq) + 1e-8f);
        float xs = 0.f;
        #pragma unroll
        for (int e = 0; e < EDIM; ++e) { const float t = acc[e] * inv; yn[pi][e] = t; xs += t * t; }
        x2[pi] = xs;
    }

    float mind[4]; int mini[4];
    #pragma unroll
    for (int pi = 0; pi < 4; ++pi) { mind[pi] = INFINITY; mini[pi] = 0x7fffffff; }

    for (int c = 0; c < 16; ++c) {
        __syncthreads();
        #pragma unroll
        for (int r = 0; r < 32; ++r) {
            const int flat = r * 256 + tid;
            const int vl = flat >> 4, e = flat & 15;
            embS[vl][e] = emb[c * 8192 + flat];
        }
        __syncthreads();
        #pragma unroll
        for (int q = 0; q < 8; ++q) {
            const int vl = lane + 64 * q;
            float ev[EDIM];
            float e2 = 0.f;
            #pragma unroll
            for (int e = 0; e < EDIM; ++e) { const float t = embS[vl][e]; ev[e] = t; e2 += t * t; }
            const int v = c * 512 + vl;
            #pragma unroll
            for (int pi = 0; pi < 4; ++pi) {
                float dot = 0.f;
                #pragma unroll
                for (int e = 0; e < EDIM; ++e) dot += yn[pi][e] * ev[e];
                const float dist = x2[pi] - 2.0f * dot + e2;
                if (dist < mind[pi]) { mind[pi] = dist; mini[pi] = v; }
            }
        }
    }
    for (int m = 1; m < 64; m <<= 1) {
        #pragma unroll
        for (int pi = 0; pi < 4; ++pi) {
            const float ov = __shfl_xor(mind[pi], m);
            const int   oi = __shfl_xor(mini[pi], m);
            if (ov < mind[pi] || (ov == mind[pi] && oi < mini[pi])) { mind[pi] = ov; mini[pi] = oi; }
        }
    }
    if (lane == 0) {
        #pragma unroll
        for (int pi = 0; pi < 4; ++pi) codes[gbase + pi] = mini[pi];
    }
}

__global__ void zero_presence(int* __restrict__ presence)
{
    presence[blockIdx.x * 256 + threadIdx.x] = 0;
}

// ---------------- Conversion: enc f32 -> encB bf16 [8192 rows m][512 k], padded rows zero ----
__global__ __launch_bounds__(128) void conv_enc(
    const float* __restrict__ enc, unsigned short* __restrict__ encB)
{
    const int m = blockIdx.x;
    const int d = threadIdx.x * 4;
    ushort4 u;
    if (m < MROWS) {
        const int b = m / 511, t = m - b * 511;
        const float4 f = *(const float4*)&enc[((size_t)(b * 512 + t)) * ENCD + d];
        u.x = f2bf(f.x); u.y = f2bf(f.y); u.z = f2bf(f.z); u.w = f2bf(f.w);
    } else {
        u.x = u.y = u.z = u.w = 0;
    }
    *(ushort4*)&encB[(size_t)m * ENCD + d] = u;
}

// ---------------- Conversion: tno f32 [512][8192] -> tnoT bf16 [8192][512] ----
__global__ __launch_bounds__(256) void conv_tnoT(
    const float* __restrict__ tno, unsigned short* __restrict__ tnoT)
{
    __shared__ float tile[32][33];
    const int n0 = blockIdx.x * 32;
    const int k0 = blockIdx.y * 32;
    const int tx = threadIdx.x & 31, ty = threadIdx.x >> 5;   // 32 x 8
    #pragma unroll
    for (int i = 0; i < 4; ++i)
        tile[ty + 8 * i][tx] = tno[(size_t)(k0 + ty + 8 * i) * NEMB + n0 + tx];
    __syncthreads();
    #pragma unroll
    for (int i = 0; i < 4; ++i)
        tnoT[(size_t)(n0 + ty + 8 * i) * ENCD + k0 + tx] = f2bf(tile[tx][ty + 8 * i]);
}

// ---------------- Kernel B: bf16 MFMA GEMM (128x128 tile, BK=64) + fused softmax partials ----
__global__ __launch_bounds__(256) void logits_mfma(
    const unsigned short* __restrict__ encB, const unsigned short* __restrict__ tnoT,
    const int* __restrict__ codes,
    float* __restrict__ pm, float* __restrict__ ps, int* __restrict__ pidx,
    float* __restrict__ tgtlog)
{
    __shared__ __align__(16) unsigned short As[128 * 64];  // [m-row][k], chunk-swizzled
    __shared__ __align__(16) unsigned short Bs[128 * 64];  // [n-row][k], chunk-swizzled
    __shared__ float redM[2][128];
    __shared__ float redS[2][128];
    __shared__ int   redI[2][128];

    const int tid  = threadIdx.x;
    const int lane = tid & 63;
    const int wave = tid >> 6;
    const int wr = wave >> 1, wc = wave & 1;

    // XCD-aware swizzle (4096 % 8 == 0 -> simple form is bijective)
    const int bid = blockIdx.x;
    const int swz = (bid & 7) * 512 + (bid >> 3);
    const int mt = swz >> 6;
    const int vt = swz & 63;
    const int m0 = mt * 128, n0 = vt * 128;

    // staging: each global_load_lds covers 8 rows x 64 k (1 KiB); 4 instrs/wave per matrix
    const int sr  = lane >> 3;              // row within 8-row group (== row & 7)
    const int sc  = lane & 7;               // linear chunk slot
    const int scs = ((sc ^ sr) << 3);       // pre-swizzled source chunk (elements)

    const size_t arowbase = (size_t)(m0 + wave * 32 + sr) * ENCD + scs;
    const size_t browbase = (size_t)(n0 + wave * 32 + sr) * ENCD + scs;

    f32x4 acc[4][4];
    #pragma unroll
    for (int i = 0; i < 4; ++i)
        #pragma unroll
        for (int j = 0; j < 4; ++j)
            acc[i][j] = (f32x4){0.f, 0.f, 0.f, 0.f};

    const int l15 = lane & 15, q = lane >> 4;

    for (int k0 = 0; k0 < ENCD; k0 += 64) {
        #pragma unroll
        for (int i = 0; i < 4; ++i) {
            gl_lds16(encB + arowbase + (size_t)i * 8 * ENCD + k0, &As[(wave * 32 + i * 8) * 64]);
            gl_lds16(tnoT + browbase + (size_t)i * 8 * ENCD + k0, &Bs[(wave * 32 + i * 8) * 64]);
        }
        __syncthreads();   // vmcnt(0) drained by compiler before barrier
        #pragma unroll
        for (int ks = 0; ks < 2; ++ks) {
            const int sw = (((ks * 4 + q) ^ (l15 & 7)) << 3);
            bf16x8 a[4], b[4];
            #pragma unroll
            for (int mi = 0; mi < 4; ++mi)
                a[mi] = *(const bf16x8*)&As[(wr * 64 + mi * 16 + l15) * 64 + sw];
            #pragma unroll
            for (int ni = 0; ni < 4; ++ni)
                b[ni] = *(const bf16x8*)&Bs[(wc * 64 + ni * 16 + l15) * 64 + sw];
            #pragma unroll
            for (int mi = 0; mi < 4; ++mi)
                #pragma unroll
                for (int ni = 0; ni < 4; ++ni)
                    acc[mi][ni] = __builtin_amdgcn_mfma_f32_16x16x32_bf16(a[mi], b[ni], acc[mi][ni], 0, 0, 0);
        }
        __syncthreads();
    }

    // Epilogue: per-row partial max / first-argmax / sumexp over this block's 128 cols.
    // D layout: row = q*4 + r, col = l15 within each 16x16 fragment (m89-verified).
    #pragma unroll
    for (int mi = 0; mi < 4; ++mi) {
        #pragma unroll
        for (int r = 0; r < 4; ++r) {
            const int rl = wr * 64 + mi * 16 + q * 4 + r;   // local row 0..127
            float lm = -INFINITY; int li = 0;
            #pragma unroll
            for (int ni = 0; ni < 4; ++ni) {
                const float v = acc[mi][ni][r];
                const int col = wc * 64 + ni * 16 + l15;
                if (v > lm) { lm = v; li = col; }           // ascending col per lane
            }
            #pragma unroll
            for (int mk = 8; mk >= 1; mk >>= 1) {
                const float ov = __shfl_xor(lm, mk);
                const int   oi = __shfl_xor(li, mk);
                if (ov > lm || (ov == lm && oi < li)) { lm = ov; li = oi; }
            }
            float le = 0.f;
            #pragma unroll
            for (int ni = 0; ni < 4; ++ni) le += __expf(acc[mi][ni][r] - lm);
            #pragma unroll
            for (int mk = 8; mk >= 1; mk >>= 1) le += __shfl_xor(le, mk);

            if (l15 == 0) { redM[wc][rl] = lm; redS[wc][rl] = le; redI[wc][rl] = li; }

            // target logit extraction
            const int mg = m0 + rl;
            if (mg < MROWS) {
                const int bb = mg / 511, tt = mg - bb * 511;
                const int tv = codes[bb * NPOS + tt + 1];
                const int rel = tv - n0 - wc * 64;
                if (rel >= 0 && rel < 64 && (rel & 15) == l15) {
                    tgtlog[mg] = acc[mi][rel >> 4][r];
                }
            }
        }
    }
    __syncthreads();
    if (tid < 128) {
        const int rl = tid;
        const int mg = m0 + rl;
        if (mg < MROWS) {
            const float mA = redM[0][rl], mB = redM[1][rl];
            const int   iA = redI[0][rl], iB = redI[1][rl];
            float gm; int gi;
            if (mB > mA || (mB == mA && iB < iA)) { gm = mB; gi = iB; } else { gm = mA; gi = iA; }
            const float S = redS[0][rl] * __expf(mA - gm) + redS[1][rl] * __expf(mB - gm);
            pm[(size_t)vt * MPAD + mg]   = gm;
            ps[(size_t)vt * MPAD + mg]   = S;
            pidx[(size_t)vt * MPAD + mg] = n0 + gi;
        }
    }
}

// ---------------- Phase 2: combine tile partials per row ----------------
__global__ __launch_bounds__(256) void combine_kernel(
    const float* __restrict__ pm, const float* __restrict__ ps,
    const int* __restrict__ pidx, const float* __restrict__ tgtlog,
    const int* __restrict__ codes, const int* __restrict__ lens,
    float* __restrict__ rnll, float* __restrict__ rcorr, float* __restrict__ rmf,
    int* __restrict__ presence)
{
    const int g = blockIdx.x * 256 + threadIdx.x;
    if (g >= MROWS) return;
    float gm = -INFINITY; int gi = 0;
    #pragma unroll 8
    for (int nt = 0; nt < NVT; ++nt) {
        const float v = pm[(size_t)nt * MPAD + g];
        if (v > gm) { gm = v; gi = pidx[(size_t)nt * MPAD + g]; }
    }
    float S = 0.f;
    #pragma unroll 8
    for (int nt = 0; nt < NVT; ++nt) S += ps[(size_t)nt * MPAD + g] * __expf(pm[(size_t)nt * MPAD + g] - gm);
    const float lse = gm + logf(S);
    const int b = g / 511, t = g - b * 511;
    const int tv = codes[b * NPOS + t + 1];
    const float nll = lse - tgtlog[g];
    const int L = lens[b];
    const int s = t + 1;
    const bool mf = (s < (L / 4)) && (4 * s + 3 < L);
    rnll[g]  = mf ? nll : 0.f;
    rcorr[g] = (mf && gi == tv) ? 1.f : 0.f;
    rmf[g]   = mf ? 1.f : 0.f;
    if (mf) presence[tv] = 1;
}

// ---------------- Phase 3: final reduction -> 4 scalars ----------------
__global__ __launch_bounds__(256) void finalize_kernel(
    const float* __restrict__ rnll, const float* __restrict__ rcorr,
    const float* __restrict__ rmf, const int* __restrict__ presence,
    float* __restrict__ out)
{
    __shared__ float sh0[256], sh1[256], sh2[256];
    __shared__ int shp[256];
    const int tid = threadIdx.x;
    float sn = 0.f, sc = 0.f, sm = 0.f; int pp = 0;
    for (int g = tid; g < MROWS; g += 256) { sn += rnll[g]; sc += rcorr[g]; sm += rmf[g]; }
    for (int v = tid; v < NEMB; v += 256) pp += presence[v];
    sh0[tid] = sn; sh1[tid] = sc; sh2[tid] = sm; shp[tid] = pp;
    __syncthreads();
    for (int s = 128; s > 0; s >>= 1) {
        if (tid < s) { sh0[tid] += sh0[tid + s]; sh1[tid] += sh1[tid + s]; sh2[tid] += sh2[tid + s]; shp[tid] += shp[tid + s]; }
        __syncthreads();
    }
    if (tid == 0) {
        const float Sm = sh2[0];
        out[0] = sh0[0] / Sm;
        out[1] = sh1[0] / Sm;
        out[2] = Sm;
        out[3] = (float)shp[0];
    }
}

extern "C" void kernel_launch(void* const* d_in, const int* in_sizes, int n_in,
                              void* d_out, int out_size, void* d_ws, size_t ws_size,
                              hipStream_t stream) {
    const float* feats = (const float*)d_in[0];
    const int*   lens  = (const int*)d_in[1];
    const float* enc   = (const float*)d_in[2];
    const float* proj  = (const float*)d_in[3];
    const float* emb   = (const float*)d_in[4];
    const float* tno   = (const float*)d_in[5];
    float* out = (float*)d_out;

    int* codes          = (int*)d_ws;                    // 8192
    int* presence       = codes + MPAD;                  // 8192
    float* pm           = (float*)(presence + MPAD);     // 64*8192
    float* ps           = pm + (size_t)NVT * MPAD;       // 64*8192
    int* pidx           = (int*)(ps + (size_t)NVT * MPAD); // 64*8192
    float* tgtlog       = (float*)(pidx + (size_t)NVT * MPAD); // 8192
    float* rnll         = tgtlog + MPAD;
    float* rcorr        = rnll + MPAD;
    float* rmf          = rcorr + MPAD;
    unsigned short* encB = (unsigned short*)(rmf + MPAD);    // 8192*512
    unsigned short* tnoT = encB + (size_t)MPAD * ENCD;       // 8192*512

    hipLaunchKernelGGL(codes_kernel, dim3(512), dim3(256), 0, stream, feats, proj, emb, codes);
    hipLaunchKernelGGL(zero_presence, dim3(NEMB / 256), dim3(256), 0, stream, presence);
    hipLaunchKernelGGL(conv_enc, dim3(MPAD), dim3(128), 0, stream, enc, encB);
    hipLaunchKernelGGL(conv_tnoT, dim3(NEMB / 32, ENCD / 32), dim3(256), 0, stream, tno, tnoT);
    hipLaunchKernelGGL(logits_mfma, dim3(64 * 64), dim3(256), 0, stream, encB, tnoT, codes, pm, ps, pidx, tgtlog);
    hipLaunchKernelGGL(combine_kernel, dim3((MROWS + 255) / 256), dim3(256), 0, stream,
                       pm, ps, pidx, tgtlog, codes, lens, rnll, rcorr, rmf, presence);
    hipLaunchKernelGGL(finalize_kernel, dim3(1), dim3(256), 0, stream, rnll, rcorr, rmf, presence, out);
}

// Round 3
// 320.861 us; speedup vs baseline: 4.6166x; 1.7609x over previous
//
#include <hip/hip_runtime.h>
#include <math.h>

typedef __attribute__((ext_vector_type(4))) float f32x4;
typedef __attribute__((ext_vector_type(8))) short bf16x8;

// Problem constants
#define NB 16
#define NT 2048
#define NMEL 80
#define NPOS 512          // stacked positions per batch
#define EDIM 16
#define NEMB 8192
#define ENCD 512
#define MROWS (NB*511)    // 8176 logit rows
#define MPAD 8192
#define NVT 64            // 8192 / 128 col tiles

__device__ __forceinline__ unsigned short f2bf(float x) {
    union { float f; unsigned u; } v; v.f = x;
    unsigned r = v.u + 0x7fffu + ((v.u >> 16) & 1u);
    return (unsigned short)(r >> 16);
}

__device__ __forceinline__ void gl_lds16(const void* gsrc, void* lds) {
    __builtin_amdgcn_global_load_lds(
        (const __attribute__((address_space(1))) unsigned int*)gsrc,
        (__attribute__((address_space(3))) unsigned int*)lds,
        16, 0, 0);
}

// ---------------- Kernel A: codes (stack -> LN -> proj -> normalize -> argmin dist) ----
__global__ __launch_bounds__(256) void codes_kernel(
    const float* __restrict__ feats, const float* __restrict__ proj,
    const float* __restrict__ emb, int* __restrict__ codes)
{
    __shared__ float embS[512][EDIM + 1];
    const int tid  = threadIdx.x;
    const int lane = tid & 63;
    const int wave = tid >> 6;
    const int gbase = blockIdx.x * 16 + wave * 4;

    float yn[4][EDIM];
    float x2[4];

    #pragma unroll
    for (int pi = 0; pi < 4; ++pi) {
        const int g = gbase + pi;
        const int b = g >> 9;
        const int i = g & 511;
        float xv[5];
        float s = 0.f, sq = 0.f;
        #pragma unroll
        for (int q = 0; q < 5; ++q) {
            const int d = lane + 64 * q;
            const int j = d / 80, k = d - j * 80;
            const float v = feats[((b * NT) + (i * 4 + j)) * NMEL + k];
            xv[q] = v; s += v; sq += v * v;
        }
        for (int m = 1; m < 64; m <<= 1) { s += __shfl_xor(s, m); sq += __shfl_xor(sq, m); }
        const float mean = s * (1.0f / 320.0f);
        const float var  = sq * (1.0f / 320.0f) - mean * mean;
        const float rstd = rsqrtf(var + 1e-6f);

        float acc[EDIM];
        #pragma unroll
        for (int e = 0; e < EDIM; ++e) acc[e] = 0.f;
        #pragma unroll
        for (int q = 0; q < 5; ++q) {
            const int d = lane + 64 * q;
            const float xn = (xv[q] - mean) * rstd;
            #pragma unroll
            for (int e = 0; e < EDIM; ++e) acc[e] += xn * proj[d * EDIM + e];
        }
        for (int m = 1; m < 64; m <<= 1) {
            #pragma unroll
            for (int e = 0; e < EDIM; ++e) acc[e] += __shfl_xor(acc[e], m);
        }
        float nsq = 0.f;
        #pragma unroll
        for (int e = 0; e < EDIM; ++e) nsq += acc[e] * acc[e];
        const float inv = 1.0f / (sqrtf(nsq) + 1e-8f);
        float xs = 0.f;
        #pragma unroll
        for (int e = 0; e < EDIM; ++e) { const float t = acc[e] * inv; yn[pi][e] = t; xs += t * t; }
        x2[pi] = xs;
    }

    float mind[4]; int mini[4];
    #pragma unroll
    for (int pi = 0; pi < 4; ++pi) { mind[pi] = INFINITY; mini[pi] = 0x7fffffff; }

    for (int c = 0; c < 16; ++c) {
        __syncthreads();
        #pragma unroll
        for (int r = 0; r < 32; ++r) {
            const int flat = r * 256 + tid;
            const int vl = flat >> 4, e = flat & 15;
            embS[vl][e] = emb[c * 8192 + flat];
        }
        __syncthreads();
        #pragma unroll
        for (int q = 0; q < 8; ++q) {
            const int vl = lane + 64 * q;
            float ev[EDIM];
            float e2 = 0.f;
            #pragma unroll
            for (int e = 0; e < EDIM; ++e) { const float t = embS[vl][e]; ev[e] = t; e2 += t * t; }
            const int v = c * 512 + vl;
            #pragma unroll
            for (int pi = 0; pi < 4; ++pi) {
                float dot = 0.f;
                #pragma unroll
                for (int e = 0; e < EDIM; ++e) dot += yn[pi][e] * ev[e];
                const float dist = x2[pi] - 2.0f * dot + e2;
                if (dist < mind[pi]) { mind[pi] = dist; mini[pi] = v; }
            }
        }
    }
    for (int m = 1; m < 64; m <<= 1) {
        #pragma unroll
        for (int pi = 0; pi < 4; ++pi) {
            const float ov = __shfl_xor(mind[pi], m);
            const int   oi = __shfl_xor(mini[pi], m);
            if (ov < mind[pi] || (ov == mind[pi] && oi < mini[pi])) { mind[pi] = ov; mini[pi] = oi; }
        }
    }
    if (lane == 0) {
        #pragma unroll
        for (int pi = 0; pi < 4; ++pi) codes[gbase + pi] = mini[pi];
    }
}

__global__ void zero_presence(int* __restrict__ presence)
{
    presence[blockIdx.x * 256 + threadIdx.x] = 0;
}

// ---------------- Conversion: enc f32 -> encB bf16 [8192 rows m][512 k], padded rows zero ----
__global__ __launch_bounds__(128) void conv_enc(
    const float* __restrict__ enc, unsigned short* __restrict__ encB)
{
    const int m = blockIdx.x;
    const int d = threadIdx.x * 4;
    ushort4 u;
    if (m < MROWS) {
        const int b = m / 511, t = m - b * 511;
        const float4 f = *(const float4*)&enc[((size_t)(b * 512 + t)) * ENCD + d];
        u.x = f2bf(f.x); u.y = f2bf(f.y); u.z = f2bf(f.z); u.w = f2bf(f.w);
    } else {
        u.x = u.y = u.z = u.w = 0;
    }
    *(ushort4*)&encB[(size_t)m * ENCD + d] = u;
}

// ---------------- Conversion: tno f32 [512][8192] -> tnoT bf16 [8192][512] ----
__global__ __launch_bounds__(256) void conv_tnoT(
    const float* __restrict__ tno, unsigned short* __restrict__ tnoT)
{
    __shared__ float tile[32][33];
    const int n0 = blockIdx.x * 32;
    const int k0 = blockIdx.y * 32;
    const int tx = threadIdx.x & 31, ty = threadIdx.x >> 5;   // 32 x 8
    #pragma unroll
    for (int i = 0; i < 4; ++i)
        tile[ty + 8 * i][tx] = tno[(size_t)(k0 + ty + 8 * i) * NEMB + n0 + tx];
    __syncthreads();
    #pragma unroll
    for (int i = 0; i < 4; ++i)
        tnoT[(size_t)(n0 + ty + 8 * i) * ENCD + k0 + tx] = f2bf(tile[tx][ty + 8 * i]);
}

// ---------------- Kernel B: bf16 MFMA GEMM (128x128 tile, BK=64) + fused softmax partials ----
__global__ __launch_bounds__(256) void logits_mfma(
    const unsigned short* __restrict__ encB, const unsigned short* __restrict__ tnoT,
    const int* __restrict__ codes,
    float* __restrict__ pm, float* __restrict__ ps, int* __restrict__ pidx,
    float* __restrict__ tgtlog)
{
    __shared__ __align__(16) unsigned short As[128 * 64];  // [m-row][k], chunk-swizzled
    __shared__ __align__(16) unsigned short Bs[128 * 64];  // [n-row][k], chunk-swizzled
    __shared__ float redM[2][128];
    __shared__ float redS[2][128];
    __shared__ int   redI[2][128];

    const int tid  = threadIdx.x;
    const int lane = tid & 63;
    const int wave = tid >> 6;
    const int wr = wave >> 1, wc = wave & 1;

    // XCD-aware mapping, mt-FASTEST within each XCD chunk:
    // XCD x (bid&7) covers mt in [8x, 8x+8), all vt. Concurrent blocks on an XCD
    // then share ~1MB of A (L2-resident) and stream B tiles once.
    const int bid = blockIdx.x;
    const int xcd = bid & 7;
    const int idx = bid >> 3;            // 0..511, consecutive on this XCD
    const int mt  = xcd * 8 + (idx & 7);
    const int vt  = idx >> 3;            // 0..63
    const int m0 = mt * 128, n0 = vt * 128;

    // staging: each global_load_lds covers 8 rows x 64 k (1 KiB); 4 instrs/wave per matrix
    const int sr  = lane >> 3;              // row within 8-row group
    const int sc  = lane & 7;               // linear chunk slot
    const int scs = ((sc ^ sr) << 3);       // pre-swizzled source chunk (elements)

    const size_t arowbase = (size_t)(m0 + wave * 32 + sr) * ENCD + scs;
    const size_t browbase = (size_t)(n0 + wave * 32 + sr) * ENCD + scs;

    f32x4 acc[4][4];
    #pragma unroll
    for (int i = 0; i < 4; ++i)
        #pragma unroll
        for (int j = 0; j < 4; ++j)
            acc[i][j] = (f32x4){0.f, 0.f, 0.f, 0.f};

    const int l15 = lane & 15, q = lane >> 4;

    for (int k0 = 0; k0 < ENCD; k0 += 64) {
        #pragma unroll
        for (int i = 0; i < 4; ++i) {
            gl_lds16(encB + arowbase + (size_t)i * 8 * ENCD + k0, &As[(wave * 32 + i * 8) * 64]);
            gl_lds16(tnoT + browbase + (size_t)i * 8 * ENCD + k0, &Bs[(wave * 32 + i * 8) * 64]);
        }
        __syncthreads();
        #pragma unroll
        for (int ks = 0; ks < 2; ++ks) {
            const int sw = (((ks * 4 + q) ^ (l15 & 7)) << 3);
            bf16x8 a[4], b[4];
            #pragma unroll
            for (int mi = 0; mi < 4; ++mi)
                a[mi] = *(const bf16x8*)&As[(wr * 64 + mi * 16 + l15) * 64 + sw];
            #pragma unroll
            for (int ni = 0; ni < 4; ++ni)
                b[ni] = *(const bf16x8*)&Bs[(wc * 64 + ni * 16 + l15) * 64 + sw];
            #pragma unroll
            for (int mi = 0; mi < 4; ++mi)
                #pragma unroll
                for (int ni = 0; ni < 4; ++ni)
                    acc[mi][ni] = __builtin_amdgcn_mfma_f32_16x16x32_bf16(a[mi], b[ni], acc[mi][ni], 0, 0, 0);
        }
        __syncthreads();
    }

    // Epilogue: per-row partial max / first-argmax / sumexp over this block's 128 cols.
    // D layout: row = q*4 + r, col = l15 (m89-verified). ALL acc indices static (rule #20).
    #pragma unroll
    for (int mi = 0; mi < 4; ++mi) {
        #pragma unroll
        for (int r = 0; r < 4; ++r) {
            const int rl = wr * 64 + mi * 16 + q * 4 + r;   // local row 0..127
            float lm = -INFINITY; int li = 0;
            #pragma unroll
            for (int ni = 0; ni < 4; ++ni) {
                const float v = acc[mi][ni][r];
                const int col = wc * 64 + ni * 16 + l15;
                if (v > lm) { lm = v; li = col; }           // ascending col per lane
            }
            #pragma unroll
            for (int mk = 8; mk >= 1; mk >>= 1) {
                const float ov = __shfl_xor(lm, mk);
                const int   oi = __shfl_xor(li, mk);
                if (ov > lm || (ov == lm && oi < li)) { lm = ov; li = oi; }
            }
            float le = 0.f;
            #pragma unroll
            for (int ni = 0; ni < 4; ++ni) le += __expf(acc[mi][ni][r] - lm);
            #pragma unroll
            for (int mk = 8; mk >= 1; mk >>= 1) le += __shfl_xor(le, mk);

            if (l15 == 0) { redM[wc][rl] = lm; redS[wc][rl] = le; redI[wc][rl] = li; }

            // target logit extraction — static acc indices only
            const int mg = m0 + rl;
            if (mg < MROWS) {
                const int bb = mg / 511, tt = mg - bb * 511;
                const int tv = codes[bb * NPOS + tt + 1];
                const int rel = tv - n0 - wc * 64;
                #pragma unroll
                for (int ni = 0; ni < 4; ++ni) {
                    if (rel >= ni * 16 && rel < ni * 16 + 16 && (rel & 15) == l15)
                        tgtlog[mg] = acc[mi][ni][r];
                }
            }
        }
    }
    __syncthreads();
    if (tid < 128) {
        const int rl = tid;
        const int mg = m0 + rl;
        if (mg < MROWS) {
            const float mA = redM[0][rl], mB = redM[1][rl];
            const int   iA = redI[0][rl], iB = redI[1][rl];
            float gm; int gi;
            if (mB > mA || (mB == mA && iB < iA)) { gm = mB; gi = iB; } else { gm = mA; gi = iA; }
            const float S = redS[0][rl] * __expf(mA - gm) + redS[1][rl] * __expf(mB - gm);
            pm[(size_t)vt * MPAD + mg]   = gm;
            ps[(size_t)vt * MPAD + mg]   = S;
            pidx[(size_t)vt * MPAD + mg] = n0 + gi;
        }
    }
}

// ---------------- Phase 2: combine tile partials per row ----------------
__global__ __launch_bounds__(256) void combine_kernel(
    const float* __restrict__ pm, const float* __restrict__ ps,
    const int* __restrict__ pidx, const float* __restrict__ tgtlog,
    const int* __restrict__ codes, const int* __restrict__ lens,
    float* __restrict__ rnll, float* __restrict__ rcorr, float* __restrict__ rmf,
    int* __restrict__ presence)
{
    const int g = blockIdx.x * 256 + threadIdx.x;
    if (g >= MROWS) return;
    float gm = -INFINITY; int gi = 0;
    #pragma unroll 8
    for (int nt = 0; nt < NVT; ++nt) {
        const float v = pm[(size_t)nt * MPAD + g];
        if (v > gm) { gm = v; gi = pidx[(size_t)nt * MPAD + g]; }
    }
    float S = 0.f;
    #pragma unroll 8
    for (int nt = 0; nt < NVT; ++nt) S += ps[(size_t)nt * MPAD + g] * __expf(pm[(size_t)nt * MPAD + g] - gm);
    const float lse = gm + logf(S);
    const int b = g / 511, t = g - b * 511;
    const int tv = codes[b * NPOS + t + 1];
    const float nll = lse - tgtlog[g];
    const int L = lens[b];
    const int s = t + 1;
    const bool mf = (s < (L / 4)) && (4 * s + 3 < L);
    rnll[g]  = mf ? nll : 0.f;
    rcorr[g] = (mf && gi == tv) ? 1.f : 0.f;
    rmf[g]   = mf ? 1.f : 0.f;
    if (mf) presence[tv] = 1;
}

// ---------------- Phase 3: final reduction -> 4 scalars ----------------
__global__ __launch_bounds__(256) void finalize_kernel(
    const float* __restrict__ rnll, const float* __restrict__ rcorr,
    const float* __restrict__ rmf, const int* __restrict__ presence,
    float* __restrict__ out)
{
    __shared__ float sh0[256], sh1[256], sh2[256];
    __shared__ int shp[256];
    const int tid = threadIdx.x;
    float sn = 0.f, sc = 0.f, sm = 0.f; int pp = 0;
    for (int g = tid; g < MROWS; g += 256) { sn += rnll[g]; sc += rcorr[g]; sm += rmf[g]; }
    for (int v = tid; v < NEMB; v += 256) pp += presence[v];
    sh0[tid] = sn; sh1[tid] = sc; sh2[tid] = sm; shp[tid] = pp;
    __syncthreads();
    for (int s = 128; s > 0; s >>= 1) {
        if (tid < s) { sh0[tid] += sh0[tid + s]; sh1[tid] += sh1[tid + s]; sh2[tid] += sh2[tid + s]; shp[tid] += shp[tid + s]; }
        __syncthreads();
    }
    if (tid == 0) {
        const float Sm = sh2[0];
        out[0] = sh0[0] / Sm;
        out[1] = sh1[0] / Sm;
        out[2] = Sm;
        out[3] = (float)shp[0];
    }
}

extern "C" void kernel_launch(void* const* d_in, const int* in_sizes, int n_in,
                              void* d_out, int out_size, void* d_ws, size_t ws_size,
                              hipStream_t stream) {
    const float* feats = (const float*)d_in[0];
    const int*   lens  = (const int*)d_in[1];
    const float* enc   = (const float*)d_in[2];
    const float* proj  = (const float*)d_in[3];
    const float* emb   = (const float*)d_in[4];
    const float* tno   = (const float*)d_in[5];
    float* out = (float*)d_out;

    int* codes          = (int*)d_ws;                    // 8192
    int* presence       = codes + MPAD;                  // 8192
    float* pm           = (float*)(presence + MPAD);     // 64*8192
    float* ps           = pm + (size_t)NVT * MPAD;       // 64*8192
    int* pidx           = (int*)(ps + (size_t)NVT * MPAD); // 64*8192
    float* tgtlog       = (float*)(pidx + (size_t)NVT * MPAD); // 8192
    float* rnll         = tgtlog + MPAD;
    float* rcorr        = rnll + MPAD;
    float* rmf          = rcorr + MPAD;
    unsigned short* encB = (unsigned short*)(rmf + MPAD);    // 8192*512
    unsigned short* tnoT = encB + (size_t)MPAD * ENCD;       // 8192*512

    hipLaunchKernelGGL(codes_kernel, dim3(512), dim3(256), 0, stream, feats, proj, emb, codes);
    hipLaunchKernelGGL(zero_presence, dim3(NEMB / 256), dim3(256), 0, stream, presence);
    hipLaunchKernelGGL(conv_enc, dim3(MPAD), dim3(128), 0, stream, enc, encB);
    hipLaunchKernelGGL(conv_tnoT, dim3(NEMB / 32, ENCD / 32), dim3(256), 0, stream, tno, tnoT);
    hipLaunchKernelGGL(logits_mfma, dim3(64 * 64), dim3(256), 0, stream, encB, tnoT, codes, pm, ps, pidx, tgtlog);
    hipLaunchKernelGGL(combine_kernel, dim3((MROWS + 255) / 256), dim3(256), 0, stream,
                       pm, ps, pidx, tgtlog, codes, lens, rnll, rcorr, rmf, presence);
    hipLaunchKernelGGL(finalize_kernel, dim3(1), dim3(256), 0, stream, rnll, rcorr, rmf, presence, out);
}

// Round 4
// 279.104 us; speedup vs baseline: 5.3073x; 1.1496x over previous
//
#include <hip/hip_runtime.h>
#include <math.h>

typedef __attribute__((ext_vector_type(4))) float f32x4;
typedef __attribute__((ext_vector_type(8))) short bf16x8;

// Problem constants
#define NB 16
#define NT 2048
#define NMEL 80
#define NPOS 512          // stacked positions per batch
#define EDIM 16
#define NEMB 8192
#define ENCD 512
#define MROWS (NB*511)    // 8176 logit rows
#define MPAD 8192
#define NVT 64            // 8192 / 128 col tiles

__device__ __forceinline__ unsigned short f2bf(float x) {
    union { float f; unsigned u; } v; v.f = x;
    unsigned r = v.u + 0x7fffu + ((v.u >> 16) & 1u);
    return (unsigned short)(r >> 16);
}

__device__ __forceinline__ void gl_lds16(const void* gsrc, void* lds) {
    __builtin_amdgcn_global_load_lds(
        (const __attribute__((address_space(1))) unsigned int*)gsrc,
        (__attribute__((address_space(3))) unsigned int*)lds,
        16, 0, 0);
}

// ---------------- Kernel A: codes (stack -> LN -> proj -> normalize -> argmin dist) ----
// Also zeroes the presence array (blocks 0..31).
__global__ __launch_bounds__(256) void codes_kernel(
    const float* __restrict__ feats, const float* __restrict__ proj,
    const float* __restrict__ emb, int* __restrict__ codes,
    int* __restrict__ presence)
{
    __shared__ float embS[512][EDIM + 1];   // col 16 = 0.5*||e||^2
    const int tid  = threadIdx.x;
    const int lane = tid & 63;
    const int wave = tid >> 6;
    const int gbase = blockIdx.x * 16 + wave * 4;

    if (blockIdx.x < 32) presence[blockIdx.x * 256 + tid] = 0;

    float yn[4][EDIM];

    #pragma unroll
    for (int pi = 0; pi < 4; ++pi) {
        const int g = gbase + pi;
        const int b = g >> 9;
        const int i = g & 511;
        float xv[5];
        float s = 0.f, sq = 0.f;
        #pragma unroll
        for (int qq = 0; qq < 5; ++qq) {
            const int d = lane + 64 * qq;
            const int j = d / 80, k = d - j * 80;
            const float v = feats[((b * NT) + (i * 4 + j)) * NMEL + k];
            xv[qq] = v; s += v; sq += v * v;
        }
        for (int m = 1; m < 64; m <<= 1) { s += __shfl_xor(s, m); sq += __shfl_xor(sq, m); }
        const float mean = s * (1.0f / 320.0f);
        const float var  = sq * (1.0f / 320.0f) - mean * mean;
        const float rstd = rsqrtf(var + 1e-6f);

        float acc[EDIM];
        #pragma unroll
        for (int e = 0; e < EDIM; ++e) acc[e] = 0.f;
        #pragma unroll
        for (int qq = 0; qq < 5; ++qq) {
            const int d = lane + 64 * qq;
            const float xn = (xv[qq] - mean) * rstd;
            #pragma unroll
            for (int e = 0; e < EDIM; ++e) acc[e] += xn * proj[d * EDIM + e];
        }
        for (int m = 1; m < 64; m <<= 1) {
            #pragma unroll
            for (int e = 0; e < EDIM; ++e) acc[e] += __shfl_xor(acc[e], m);
        }
        float nsq = 0.f;
        #pragma unroll
        for (int e = 0; e < EDIM; ++e) nsq += acc[e] * acc[e];
        const float inv = 1.0f / (sqrtf(nsq) + 1e-8f);
        #pragma unroll
        for (int e = 0; e < EDIM; ++e) yn[pi][e] = acc[e] * inv;
    }

    // argmin over score = 0.5*||e||^2 - <y,e>  (order-equivalent to the distance)
    float mind[4]; int mini[4];
    #pragma unroll
    for (int pi = 0; pi < 4; ++pi) { mind[pi] = INFINITY; mini[pi] = 0x7fffffff; }

    for (int c = 0; c < 16; ++c) {
        __syncthreads();
        #pragma unroll
        for (int r = 0; r < 32; ++r) {
            const int flat = r * 256 + tid;
            const int vl = flat >> 4, e = flat & 15;
            embS[vl][e] = emb[c * 8192 + flat];
        }
        __syncthreads();
        #pragma unroll
        for (int rr = 0; rr < 2; ++rr) {
            const int vl = tid * 2 + rr;
            float e2 = 0.f;
            #pragma unroll
            for (int e = 0; e < EDIM; ++e) e2 += embS[vl][e] * embS[vl][e];
            embS[vl][EDIM] = 0.5f * e2;
        }
        __syncthreads();
        #pragma unroll
        for (int qq = 0; qq < 8; ++qq) {
            const int vl = lane + 64 * qq;
            float ev[EDIM];
            #pragma unroll
            for (int e = 0; e < EDIM; ++e) ev[e] = embS[vl][e];
            const float h2 = embS[vl][EDIM];
            const int v = c * 512 + vl;
            #pragma unroll
            for (int pi = 0; pi < 4; ++pi) {
                float dot = 0.f;
                #pragma unroll
                for (int e = 0; e < EDIM; ++e) dot += yn[pi][e] * ev[e];
                const float sc = h2 - dot;
                if (sc < mind[pi]) { mind[pi] = sc; mini[pi] = v; }
            }
        }
    }
    for (int m = 1; m < 64; m <<= 1) {
        #pragma unroll
        for (int pi = 0; pi < 4; ++pi) {
            const float ov = __shfl_xor(mind[pi], m);
            const int   oi = __shfl_xor(mini[pi], m);
            if (ov < mind[pi] || (ov == mind[pi] && oi < mini[pi])) { mind[pi] = ov; mini[pi] = oi; }
        }
    }
    if (lane == 0) {
        #pragma unroll
        for (int pi = 0; pi < 4; ++pi) codes[gbase + pi] = mini[pi];
    }
}

// ---------------- Conversion: enc f32 -> encB bf16 [8192 rows m][512 k], padded rows zero ----
__global__ __launch_bounds__(128) void conv_enc(
    const float* __restrict__ enc, unsigned short* __restrict__ encB)
{
    const int m = blockIdx.x;
    const int d = threadIdx.x * 4;
    ushort4 u;
    if (m < MROWS) {
        const int b = m / 511, t = m - b * 511;
        const float4 f = *(const float4*)&enc[((size_t)(b * 512 + t)) * ENCD + d];
        u.x = f2bf(f.x); u.y = f2bf(f.y); u.z = f2bf(f.z); u.w = f2bf(f.w);
    } else {
        u.x = u.y = u.z = u.w = 0;
    }
    *(ushort4*)&encB[(size_t)m * ENCD + d] = u;
}

// ---------------- Conversion: tno f32 [512][8192] -> tnoT bf16 [8192][512] ----
__global__ __launch_bounds__(256) void conv_tnoT(
    const float* __restrict__ tno, unsigned short* __restrict__ tnoT)
{
    __shared__ float tile[32][33];
    const int n0 = blockIdx.x * 32;
    const int k0 = blockIdx.y * 32;
    const int tx = threadIdx.x & 31, ty = threadIdx.x >> 5;   // 32 x 8
    #pragma unroll
    for (int i = 0; i < 4; ++i)
        tile[ty + 8 * i][tx] = tno[(size_t)(k0 + ty + 8 * i) * NEMB + n0 + tx];
    __syncthreads();
    #pragma unroll
    for (int i = 0; i < 4; ++i)
        tnoT[(size_t)(n0 + ty + 8 * i) * ENCD + k0 + tx] = f2bf(tile[tx][ty + 8 * i]);
}

// ---------------- Kernel B: bf16 MFMA GEMM, BK=32, triple-buffered counted-vmcnt pipeline ----
__global__ __launch_bounds__(256, 3) void logits_mfma(
    const unsigned short* __restrict__ encB, const unsigned short* __restrict__ tnoT,
    const int* __restrict__ codes,
    float* __restrict__ pm, float* __restrict__ ps, int* __restrict__ pidx,
    float* __restrict__ tgtlog)
{
    __shared__ __align__(16) unsigned short As3[3][128 * 32];
    __shared__ __align__(16) unsigned short Bs3[3][128 * 32];
    __shared__ float redM[2][128];
    __shared__ float redS[2][128];
    __shared__ int   redI[2][128];

    const int tid  = threadIdx.x;
    const int lane = tid & 63;
    const int wave = tid >> 6;
    const int wr = wave >> 1, wc = wave & 1;

    // XCD-aware mapping, mt-fastest within each XCD chunk (L2: A resident, B streamed once/8mt)
    const int bid = blockIdx.x;
    const int xcd = bid & 7;
    const int idx = bid >> 3;
    const int mt  = xcd * 8 + (idx & 7);
    const int vt  = idx >> 3;
    const int m0 = mt * 128, n0 = vt * 128;

    // staging lane constants: rows of 32 bf16 (64B); 16B chunks, source pre-swizzled
    // involution: lds slot s of row r holds global chunk s ^ ((r>>1)&3)
    const int rb  = lane >> 2;                               // 0..15 row within 16-row group
    const int gc8 = ((lane & 3) ^ ((lane >> 3) & 3)) * 8;    // pre-swizzled global chunk (elems)
    const size_t abase0 = (size_t)(m0 + wave * 32 + rb) * ENCD + gc8;
    const size_t bbase0 = (size_t)(n0 + wave * 32 + rb) * ENCD + gc8;

#define STAGE(t, buf)                                                                        \
    {                                                                                        \
        const int k0s = (t) * 32;                                                            \
        gl_lds16(encB + abase0 + k0s,              &As3[buf][(wave * 32) * 32]);             \
        gl_lds16(tnoT + bbase0 + k0s,              &Bs3[buf][(wave * 32) * 32]);             \
        gl_lds16(encB + abase0 + 16 * ENCD + k0s,  &As3[buf][(wave * 32 + 16) * 32]);        \
        gl_lds16(tnoT + bbase0 + 16 * ENCD + k0s,  &Bs3[buf][(wave * 32 + 16) * 32]);        \
    }

    f32x4 acc[4][4];
    #pragma unroll
    for (int i = 0; i < 4; ++i)
        #pragma unroll
        for (int j = 0; j < 4; ++j)
            acc[i][j] = (f32x4){0.f, 0.f, 0.f, 0.f};

    const int l15 = lane & 15, q = lane >> 4;
    const int ca = (q ^ ((l15 >> 1) & 3)) * 8;   // swizzled chunk offset for fragment reads

    STAGE(0, 0);
    STAGE(1, 1);

    #pragma unroll
    for (int t = 0; t < 16; ++t) {
        // tile t ready when only the newer stage's 4 loads remain in flight
        if (t < 15) { asm volatile("s_waitcnt vmcnt(4)" ::: "memory"); }
        else        { asm volatile("s_waitcnt vmcnt(0)" ::: "memory"); }
        __builtin_amdgcn_s_barrier();
        __builtin_amdgcn_sched_barrier(0);
        if (t + 2 < 16) {
            const int nb = (t + 2) % 3;
            STAGE(t + 2, nb);
        }
        const unsigned short* Ab = As3[t % 3];
        const unsigned short* Bb = Bs3[t % 3];
        bf16x8 a[4], b[4];
        #pragma unroll
        for (int mi = 0; mi < 4; ++mi)
            a[mi] = *(const bf16x8*)&Ab[(wr * 64 + mi * 16 + l15) * 32 + ca];
        #pragma unroll
        for (int ni = 0; ni < 4; ++ni)
            b[ni] = *(const bf16x8*)&Bb[(wc * 64 + ni * 16 + l15) * 32 + ca];
        __builtin_amdgcn_s_setprio(1);
        #pragma unroll
        for (int mi = 0; mi < 4; ++mi)
            #pragma unroll
            for (int ni = 0; ni < 4; ++ni)
                acc[mi][ni] = __builtin_amdgcn_mfma_f32_16x16x32_bf16(a[mi], b[ni], acc[mi][ni], 0, 0, 0);
        __builtin_amdgcn_s_setprio(0);
    }

    // Epilogue: per-row partial max / first-argmax / sumexp over this block's 128 cols.
    // D layout: row = q*4 + r, col = l15 (m89-verified). ALL acc indices static (rule #20).
    #pragma unroll
    for (int mi = 0; mi < 4; ++mi) {
        #pragma unroll
        for (int r = 0; r < 4; ++r) {
            const int rl = wr * 64 + mi * 16 + q * 4 + r;   // local row 0..127
            float lm = -INFINITY; int li = 0;
            #pragma unroll
            for (int ni = 0; ni < 4; ++ni) {
                const float v = acc[mi][ni][r];
                const int col = wc * 64 + ni * 16 + l15;
                if (v > lm) { lm = v; li = col; }           // ascending col per lane
            }
            #pragma unroll
            for (int mk = 8; mk >= 1; mk >>= 1) {
                const float ov = __shfl_xor(lm, mk);
                const int   oi = __shfl_xor(li, mk);
                if (ov > lm || (ov == lm && oi < li)) { lm = ov; li = oi; }
            }
            float le = 0.f;
            #pragma unroll
            for (int ni = 0; ni < 4; ++ni) le += __expf(acc[mi][ni][r] - lm);
            #pragma unroll
            for (int mk = 8; mk >= 1; mk >>= 1) le += __shfl_xor(le, mk);

            if (l15 == 0) { redM[wc][rl] = lm; redS[wc][rl] = le; redI[wc][rl] = li; }

            // target logit extraction — static acc indices only
            const int mg = m0 + rl;
            if (mg < MROWS) {
                const int bb = mg / 511, tt = mg - bb * 511;
                const int tv = codes[bb * NPOS + tt + 1];
                const int rel = tv - n0 - wc * 64;
                #pragma unroll
                for (int ni = 0; ni < 4; ++ni) {
                    if (rel >= ni * 16 && rel < ni * 16 + 16 && (rel & 15) == l15)
                        tgtlog[mg] = acc[mi][ni][r];
                }
            }
        }
    }
    __syncthreads();
    if (tid < 128) {
        const int rl = tid;
        const int mg = m0 + rl;
        if (mg < MROWS) {
            const float mA = redM[0][rl], mB = redM[1][rl];
            const int   iA = redI[0][rl], iB = redI[1][rl];
            float gm; int gi;
            if (mB > mA || (mB == mA && iB < iA)) { gm = mB; gi = iB; } else { gm = mA; gi = iA; }
            const float S = redS[0][rl] * __expf(mA - gm) + redS[1][rl] * __expf(mB - gm);
            pm[(size_t)vt * MPAD + mg]   = gm;
            ps[(size_t)vt * MPAD + mg]   = S;
            pidx[(size_t)vt * MPAD + mg] = n0 + gi;
        }
    }
#undef STAGE
}

// ---------------- Phase 2: combine tile partials per row ----------------
__global__ __launch_bounds__(256) void combine_kernel(
    const float* __restrict__ pm, const float* __restrict__ ps,
    const int* __restrict__ pidx, const float* __restrict__ tgtlog,
    const int* __restrict__ codes, const int* __restrict__ lens,
    float* __restrict__ rnll, float* __restrict__ rcorr, float* __restrict__ rmf,
    int* __restrict__ presence)
{
    const int g = blockIdx.x * 256 + threadIdx.x;
    if (g >= MROWS) return;
    float gm = -INFINITY; int gi = 0;
    #pragma unroll 8
    for (int nt = 0; nt < NVT; ++nt) {
        const float v = pm[(size_t)nt * MPAD + g];
        if (v > gm) { gm = v; gi = pidx[(size_t)nt * MPAD + g]; }
    }
    float S = 0.f;
    #pragma unroll 8
    for (int nt = 0; nt < NVT; ++nt) S += ps[(size_t)nt * MPAD + g] * __expf(pm[(size_t)nt * MPAD + g] - gm);
    const float lse = gm + logf(S);
    const int b = g / 511, t = g - b * 511;
    const int tv = codes[b * NPOS + t + 1];
    const float nll = lse - tgtlog[g];
    const int L = lens[b];
    const int s = t + 1;
    const bool mf = (s < (L / 4)) && (4 * s + 3 < L);
    rnll[g]  = mf ? nll : 0.f;
    rcorr[g] = (mf && gi == tv) ? 1.f : 0.f;
    rmf[g]   = mf ? 1.f : 0.f;
    if (mf) presence[tv] = 1;
}

// ---------------- Phase 3: final reduction -> 4 scalars ----------------
__global__ __launch_bounds__(256) void finalize_kernel(
    const float* __restrict__ rnll, const float* __restrict__ rcorr,
    const float* __restrict__ rmf, const int* __restrict__ presence,
    float* __restrict__ out)
{
    __shared__ float sh0[256], sh1[256], sh2[256];
    __shared__ int shp[256];
    const int tid = threadIdx.x;
    float sn = 0.f, sc = 0.f, sm = 0.f; int pp = 0;
    for (int g = tid; g < MROWS; g += 256) { sn += rnll[g]; sc += rcorr[g]; sm += rmf[g]; }
    for (int v = tid; v < NEMB; v += 256) pp += presence[v];
    sh0[tid] = sn; sh1[tid] = sc; sh2[tid] = sm; shp[tid] = pp;
    __syncthreads();
    for (int s = 128; s > 0; s >>= 1) {
        if (tid < s) { sh0[tid] += sh0[tid + s]; sh1[tid] += sh1[tid + s]; sh2[tid] += sh2[tid + s]; shp[tid] += shp[tid + s]; }
        __syncthreads();
    }
    if (tid == 0) {
        const float Sm = sh2[0];
        out[0] = sh0[0] / Sm;
        out[1] = sh1[0] / Sm;
        out[2] = Sm;
        out[3] = (float)shp[0];
    }
}

extern "C" void kernel_launch(void* const* d_in, const int* in_sizes, int n_in,
                              void* d_out, int out_size, void* d_ws, size_t ws_size,
                              hipStream_t stream) {
    const float* feats = (const float*)d_in[0];
    const int*   lens  = (const int*)d_in[1];
    const float* enc   = (const float*)d_in[2];
    const float* proj  = (const float*)d_in[3];
    const float* emb   = (const float*)d_in[4];
    const float* tno   = (const float*)d_in[5];
    float* out = (float*)d_out;

    int* codes          = (int*)d_ws;                    // 8192
    int* presence       = codes + MPAD;                  // 8192
    float* pm           = (float*)(presence + MPAD);     // 64*8192
    float* ps           = pm + (size_t)NVT * MPAD;       // 64*8192
    int* pidx           = (int*)(ps + (size_t)NVT * MPAD); // 64*8192
    float* tgtlog       = (float*)(pidx + (size_t)NVT * MPAD); // 8192
    float* rnll         = tgtlog + MPAD;
    float* rcorr        = rnll + MPAD;
    float* rmf          = rcorr + MPAD;
    unsigned short* encB = (unsigned short*)(rmf + MPAD);    // 8192*512
    unsigned short* tnoT = encB + (size_t)MPAD * ENCD;       // 8192*512

    hipLaunchKernelGGL(codes_kernel, dim3(512), dim3(256), 0, stream, feats, proj, emb, codes, presence);
    hipLaunchKernelGGL(conv_enc, dim3(MPAD), dim3(128), 0, stream, enc, encB);
    hipLaunchKernelGGL(conv_tnoT, dim3(NEMB / 32, ENCD / 32), dim3(256), 0, stream, tno, tnoT);
    hipLaunchKernelGGL(logits_mfma, dim3(64 * 64), dim3(256), 0, stream, encB, tnoT, codes, pm, ps, pidx, tgtlog);
    hipLaunchKernelGGL(combine_kernel, dim3((MROWS + 255) / 256), dim3(256), 0, stream,
                       pm, ps, pidx, tgtlog, codes, lens, rnll, rcorr, rmf, presence);
    hipLaunchKernelGGL(finalize_kernel, dim3(1), dim3(256), 0, stream, rnll, rcorr, rmf, presence, out);
}